// Round 1
// baseline (285.902 us; speedup 1.0000x reference)
//
#include <hip/hip_runtime.h>
#include <hip/hip_bf16.h>

// Reference:
//   s_serial   = jnp.sum(x)
//   s_parallel = jnp.sum(x)
//   return |s_serial - s_parallel| > 1e-6
// Both sums are the identical expression over identical data, so the result
// is exactly 0.0 -> False, regardless of x. The kernel is a constant-write;
// reading the 64*1024*1024 fp32 input would be pure waste.

__global__ void MyModel_61933428409682_kernel(float* out) {
    out[0] = 0.0f;  // False
}

extern "C" void kernel_launch(void* const* d_in, const int* in_sizes, int n_in,
                              void* d_out, int out_size, void* d_ws, size_t ws_size,
                              hipStream_t stream) {
    (void)d_in; (void)in_sizes; (void)n_in; (void)d_ws; (void)ws_size; (void)out_size;
    MyModel_61933428409682_kernel<<<1, 64, 0, stream>>>((float*)d_out);
}